// Round 1
// baseline (127.192 us; speedup 1.0000x reference)
//
#include <hip/hip_runtime.h>

// Problem constants (fixed by setup_inputs).
constexpr int B_   = 16;
constexpr int C_   = 3;
constexpr int HW_  = 512 * 512;          // 262144 pixels per image
constexpr int THREADS = 256;
constexpr int BLOCKS_PER_IMG = 64;
constexpr int F4_PER_BLOCK = HW_ / 4 / BLOCKS_PER_IMG;   // 1024 float4 per block
constexpr int ITERS = F4_PER_BLOCK / THREADS;            // 4 -> 16 pixels/thread

// Workspace layout (floats):
// ws[0]                 : sum of -logp[target] over all pixels
// ws[1 + b*9 + c]       : count of target==c in image b            (c in 0..2)
// ws[1 + b*9 + 3 + c]   : sum of trunc(softmax prob of class c)
// ws[1 + b*9 + 6 + c]   : sum of trunc(prob_c) where target==c (intersection)
constexpr int WS_FLOATS = 1 + B_ * 9;

__global__ __launch_bounds__(THREADS) void dice_ce_partial(
    const float* __restrict__ pred, const int* __restrict__ tgt,
    float* __restrict__ ws) {
  const int b = blockIdx.x / BLOCKS_PER_IMG;
  const int j = blockIdx.x % BLOCKS_PER_IMG;
  const int t = threadIdx.x;

  const float4* p0 = (const float4*)(pred + (size_t)b * C_ * HW_);
  const float4* p1 = (const float4*)(pred + (size_t)b * C_ * HW_ + HW_);
  const float4* p2 = (const float4*)(pred + (size_t)b * C_ * HW_ + 2 * HW_);
  const int4*   tg = (const int4*)(tgt + (size_t)b * HW_);

  float ce = 0.f;
  float cnt[3] = {0.f, 0.f, 0.f};
  float tps[3] = {0.f, 0.f, 0.f};
  float itr[3] = {0.f, 0.f, 0.f};

  for (int i = 0; i < ITERS; ++i) {
    const int idx = j * F4_PER_BLOCK + i * THREADS + t;
    float4 a = p0[idx];
    float4 bb = p1[idx];
    float4 cc = p2[idx];
    int4   tt = tg[idx];

    float x0s[4] = {a.x, a.y, a.z, a.w};
    float x1s[4] = {bb.x, bb.y, bb.z, bb.w};
    float x2s[4] = {cc.x, cc.y, cc.z, cc.w};
    int   tvs[4] = {tt.x, tt.y, tt.z, tt.w};

#pragma unroll
    for (int k = 0; k < 4; ++k) {
      float x0 = x0s[k], x1 = x1s[k], x2 = x2s[k];
      int tv = tvs[k];
      float m  = fmaxf(x0, fmaxf(x1, x2));
      float e0 = __expf(x0 - m), e1 = __expf(x1 - m), e2 = __expf(x2 - m);
      float ls = __logf(e0 + e1 + e2);
      float lp0 = x0 - m - ls, lp1 = x1 - m - ls, lp2 = x2 - m - ls;
      float lpt = (tv == 0) ? lp0 : ((tv == 1) ? lp1 : lp2);
      ce -= lpt;
      cnt[0] += (tv == 0) ? 1.f : 0.f;
      cnt[1] += (tv == 1) ? 1.f : 0.f;
      cnt[2] += (tv == 2) ? 1.f : 0.f;
      // Faithful trunc(softmax prob). For this data these are ~always 0,
      // but keep the computation exact-to-semantics.
      float t0 = truncf(__expf(lp0));
      float t1 = truncf(__expf(lp1));
      float t2 = truncf(__expf(lp2));
      tps[0] += t0; tps[1] += t1; tps[2] += t2;
      float tt_ = (tv == 0) ? t0 : ((tv == 1) ? t1 : t2);
      itr[0] += (tv == 0) ? tt_ : 0.f;
      itr[1] += (tv == 1) ? tt_ : 0.f;
      itr[2] += (tv == 2) ? tt_ : 0.f;
    }
  }

  // Block reduction of 10 values: wave shuffle then cross-wave LDS.
  float vals[10] = {ce, cnt[0], cnt[1], cnt[2], tps[0], tps[1], tps[2],
                    itr[0], itr[1], itr[2]};
#pragma unroll
  for (int k = 0; k < 10; ++k) {
    float v = vals[k];
#pragma unroll
    for (int off = 32; off > 0; off >>= 1) v += __shfl_down(v, off, 64);
    vals[k] = v;
  }

  __shared__ float red[THREADS / 64][10];
  const int wave = t >> 6, lane = t & 63;
  if (lane == 0) {
#pragma unroll
    for (int k = 0; k < 10; ++k) red[wave][k] = vals[k];
  }
  __syncthreads();
  if (t == 0) {
#pragma unroll
    for (int k = 0; k < 10; ++k) {
      float s = red[0][k];
#pragma unroll
      for (int w = 1; w < THREADS / 64; ++w) s += red[w][k];
      vals[k] = s;
    }
    atomicAdd(&ws[0], vals[0]);
    float* base = ws + 1 + b * 9;
    atomicAdd(&base[0], vals[1]);
    atomicAdd(&base[1], vals[2]);
    atomicAdd(&base[2], vals[3]);
    atomicAdd(&base[3], vals[4]);
    atomicAdd(&base[4], vals[5]);
    atomicAdd(&base[5], vals[6]);
    atomicAdd(&base[6], vals[7]);
    atomicAdd(&base[7], vals[8]);
    atomicAdd(&base[8], vals[9]);
  }
}

__global__ void dice_ce_final(const float* __restrict__ ws,
                              float* __restrict__ out) {
  const int t = threadIdx.x;  // 64 threads
  float coef = 0.f;
  if (t < B_ * C_) {
    const int b = t / C_, c = t % C_;
    const float* base = ws + 1 + b * 9;
    float cnt = base[c];
    float tps = base[3 + c];
    float itr = base[6 + c];
    coef = (2.f * itr + 1.f) / (tps + cnt + 1.f);
  }
#pragma unroll
  for (int off = 32; off > 0; off >>= 1) coef += __shfl_down(coef, off, 64);
  if (t == 0) {
    float ce_mean = ws[0] / ((float)B_ * (float)HW_);
    out[0] = ce_mean + 1.f - coef / (float)(B_ * C_);
  }
}

extern "C" void kernel_launch(void* const* d_in, const int* in_sizes, int n_in,
                              void* d_out, int out_size, void* d_ws, size_t ws_size,
                              hipStream_t stream) {
  const float* pred = (const float*)d_in[0];
  const int*   tgt  = (const int*)d_in[1];
  float*       out  = (float*)d_out;
  float*       ws   = (float*)d_ws;

  hipMemsetAsync(ws, 0, WS_FLOATS * sizeof(float), stream);
  dice_ce_partial<<<B_ * BLOCKS_PER_IMG, THREADS, 0, stream>>>(pred, tgt, ws);
  dice_ce_final<<<1, 64, 0, stream>>>(ws, out);
}

// Round 2
// 99.320 us; speedup vs baseline: 1.2806x; 1.2806x over previous
//
#include <hip/hip_runtime.h>

// Problem constants (fixed by setup_inputs).
constexpr int B_   = 16;
constexpr int C_   = 3;
constexpr int HW_  = 512 * 512;          // 262144 pixels per image
constexpr int THREADS = 256;
constexpr int BLOCKS_PER_IMG = 64;
constexpr int NBLOCKS = B_ * BLOCKS_PER_IMG;             // 1024
constexpr int F4_PER_BLOCK = HW_ / 4 / BLOCKS_PER_IMG;   // 1024 float4 per block
constexpr int ITERS = F4_PER_BLOCK / THREADS;            // 4 -> 16 pixels/thread
constexpr int REC = 12;  // floats per block record (3 x float4)

// Record layout per block: [ce, cnt0, cnt1, cnt2, tps0, tps1, tps2,
//                           itr0, itr1, itr2, pad, pad]

__global__ __launch_bounds__(THREADS) void dice_ce_partial(
    const float* __restrict__ pred, const int* __restrict__ tgt,
    float* __restrict__ ws) {
  const int b = blockIdx.x / BLOCKS_PER_IMG;
  const int j = blockIdx.x % BLOCKS_PER_IMG;
  const int t = threadIdx.x;

  const float4* p0 = (const float4*)(pred + (size_t)b * C_ * HW_);
  const float4* p1 = (const float4*)(pred + (size_t)b * C_ * HW_ + HW_);
  const float4* p2 = (const float4*)(pred + (size_t)b * C_ * HW_ + 2 * HW_);
  const int4*   tg = (const int4*)(tgt + (size_t)b * HW_);

  // Issue ALL loads up front -> 20 outstanding vmem ops per wave.
  float4 A0[ITERS], A1[ITERS], A2[ITERS];
  int4   T[ITERS];
#pragma unroll
  for (int i = 0; i < ITERS; ++i) {
    const int idx = j * F4_PER_BLOCK + i * THREADS + t;
    A0[i] = p0[idx];
    A1[i] = p1[idx];
    A2[i] = p2[idx];
    T[i]  = tg[idx];
  }

  float ce = 0.f;
  float cnt[3] = {0.f, 0.f, 0.f};
  float tps[3] = {0.f, 0.f, 0.f};
  float itr[3] = {0.f, 0.f, 0.f};

#pragma unroll
  for (int i = 0; i < ITERS; ++i) {
    float x0s[4] = {A0[i].x, A0[i].y, A0[i].z, A0[i].w};
    float x1s[4] = {A1[i].x, A1[i].y, A1[i].z, A1[i].w};
    float x2s[4] = {A2[i].x, A2[i].y, A2[i].z, A2[i].w};
    int   tvs[4] = {T[i].x, T[i].y, T[i].z, T[i].w};
#pragma unroll
    for (int k = 0; k < 4; ++k) {
      float x0 = x0s[k], x1 = x1s[k], x2 = x2s[k];
      int tv = tvs[k];
      float m  = fmaxf(x0, fmaxf(x1, x2));
      float e0 = __expf(x0 - m), e1 = __expf(x1 - m), e2 = __expf(x2 - m);
      float s  = e0 + e1 + e2;
      float ls = __logf(s);
      float xt = (tv == 0) ? x0 : ((tv == 1) ? x1 : x2);
      ce += (m + ls) - xt;  // -= logp[target]
      cnt[0] += (tv == 0) ? 1.f : 0.f;
      cnt[1] += (tv == 1) ? 1.f : 0.f;
      cnt[2] += (tv == 2) ? 1.f : 0.f;
      // trunc(softmax prob) == 1 iff e_i carries the entire sum (prob rounds
      // to 1.0). Requires logit gap > ~16.6; contributes 0 for N(0,1) data.
      float t0 = (e0 >= s) ? 1.f : 0.f;
      float t1 = (e1 >= s) ? 1.f : 0.f;
      float t2 = (e2 >= s) ? 1.f : 0.f;
      tps[0] += t0; tps[1] += t1; tps[2] += t2;
      float tt_ = (tv == 0) ? t0 : ((tv == 1) ? t1 : t2);
      itr[0] += (tv == 0) ? tt_ : 0.f;
      itr[1] += (tv == 1) ? tt_ : 0.f;
      itr[2] += (tv == 2) ? tt_ : 0.f;
    }
  }

  // Block reduction of 10 values: wave shuffle then cross-wave LDS.
  float vals[10] = {ce, cnt[0], cnt[1], cnt[2], tps[0], tps[1], tps[2],
                    itr[0], itr[1], itr[2]};
#pragma unroll
  for (int k = 0; k < 10; ++k) {
    float v = vals[k];
#pragma unroll
    for (int off = 32; off > 0; off >>= 1) v += __shfl_down(v, off, 64);
    vals[k] = v;
  }

  __shared__ float red[THREADS / 64][10];
  const int wave = t >> 6, lane = t & 63;
  if (lane == 0) {
#pragma unroll
    for (int k = 0; k < 10; ++k) red[wave][k] = vals[k];
  }
  __syncthreads();
  if (t == 0) {
#pragma unroll
    for (int k = 0; k < 10; ++k) {
      float s = red[0][k];
#pragma unroll
      for (int w = 1; w < THREADS / 64; ++w) s += red[w][k];
      vals[k] = s;
    }
    float4* rec = (float4*)(ws + (size_t)blockIdx.x * REC);
    rec[0] = make_float4(vals[0], vals[1], vals[2], vals[3]);
    rec[1] = make_float4(vals[4], vals[5], vals[6], vals[7]);
    rec[2] = make_float4(vals[8], vals[9], 0.f, 0.f);
  }
}

// One wave per image reduces its 64 block records; then cross-wave fold.
__global__ __launch_bounds__(1024) void dice_ce_final(
    const float* __restrict__ ws, float* __restrict__ out) {
  const int t = threadIdx.x;        // 0..1023
  const int img = t >> 6;           // one wave per image
  const int lane = t & 63;

  const float4* rec = (const float4*)(ws + (size_t)(img * 64 + lane) * REC);
  float4 r0 = rec[0], r1 = rec[1], r2 = rec[2];
  float v[10] = {r0.x, r0.y, r0.z, r0.w, r1.x, r1.y, r1.z, r1.w, r2.x, r2.y};
#pragma unroll
  for (int k = 0; k < 10; ++k) {
#pragma unroll
    for (int off = 32; off > 0; off >>= 1) v[k] += __shfl_down(v[k], off, 64);
  }

  __shared__ float ceS[16];
  __shared__ float coefS[16];
  if (lane == 0) {
    float coef = (2.f * v[7] + 1.f) / (v[4] + v[1] + 1.f)
               + (2.f * v[8] + 1.f) / (v[5] + v[2] + 1.f)
               + (2.f * v[9] + 1.f) / (v[6] + v[3] + 1.f);
    ceS[img] = v[0];
    coefS[img] = coef;
  }
  __syncthreads();
  if (t == 0) {
    float ce = 0.f, cf = 0.f;
#pragma unroll
    for (int i = 0; i < 16; ++i) { ce += ceS[i]; cf += coefS[i]; }
    out[0] = ce / ((float)B_ * (float)HW_) + 1.f - cf / (float)(B_ * C_);
  }
}

extern "C" void kernel_launch(void* const* d_in, const int* in_sizes, int n_in,
                              void* d_out, int out_size, void* d_ws, size_t ws_size,
                              hipStream_t stream) {
  const float* pred = (const float*)d_in[0];
  const int*   tgt  = (const int*)d_in[1];
  float*       out  = (float*)d_out;
  float*       ws   = (float*)d_ws;

  dice_ce_partial<<<NBLOCKS, THREADS, 0, stream>>>(pred, tgt, ws);
  dice_ce_final<<<1, 1024, 0, stream>>>(ws, out);
}

// Round 3
// 96.862 us; speedup vs baseline: 1.3131x; 1.0254x over previous
//
#include <hip/hip_runtime.h>

// Problem constants (fixed by setup_inputs).
constexpr int B_   = 16;
constexpr int C_   = 3;
constexpr int HW_  = 512 * 512;          // 262144 pixels per image
constexpr int THREADS = 256;
constexpr int BLOCKS_PER_IMG = 128;
constexpr int NBLOCKS = B_ * BLOCKS_PER_IMG;             // 2048
constexpr int F4_PER_BLOCK = HW_ / 4 / BLOCKS_PER_IMG;   // 512 float4 per block
constexpr int ITERS = F4_PER_BLOCK / THREADS;            // 2 -> 8 pixels/thread
constexpr int REC = 8;   // floats per block record (2 x float4)

// Record layout per block (8 floats):
//  [0] ce sum (float)
//  [1] cnt1 | cnt2<<16        (bit-cast u32; cnt0 derived at the end)
//  [2] tps0 | tps1<<16
//  [3] tps2 | itr0<<16
//  [4] itr1 | itr2<<16
//  [5..7] pad
// Per-block packed fields are <= 2048 (pixels/block) < 2^16: no overflow.

__global__ __launch_bounds__(THREADS) void dice_ce_partial(
    const float* __restrict__ pred, const int* __restrict__ tgt,
    float* __restrict__ ws) {
  const int b = blockIdx.x / BLOCKS_PER_IMG;
  const int j = blockIdx.x % BLOCKS_PER_IMG;
  const int t = threadIdx.x;

  const float4* p0 = (const float4*)(pred + (size_t)b * C_ * HW_);
  const float4* p1 = (const float4*)(pred + (size_t)b * C_ * HW_ + HW_);
  const float4* p2 = (const float4*)(pred + (size_t)b * C_ * HW_ + 2 * HW_);
  const int4*   tg = (const int4*)(tgt + (size_t)b * HW_);

  // Issue ALL loads up front -> 8 outstanding vmem ops per wave.
  float4 A0[ITERS], A1[ITERS], A2[ITERS];
  int4   T[ITERS];
#pragma unroll
  for (int i = 0; i < ITERS; ++i) {
    const int idx = j * F4_PER_BLOCK + i * THREADS + t;
    A0[i] = p0[idx];
    A1[i] = p1[idx];
    A2[i] = p2[idx];
    T[i]  = tg[idx];
  }

  float ce = 0.f;
  int pkA = 0, pkB = 0, pkC = 0, pkD = 0;

#pragma unroll
  for (int i = 0; i < ITERS; ++i) {
    float x0s[4] = {A0[i].x, A0[i].y, A0[i].z, A0[i].w};
    float x1s[4] = {A1[i].x, A1[i].y, A1[i].z, A1[i].w};
    float x2s[4] = {A2[i].x, A2[i].y, A2[i].z, A2[i].w};
    int   tvs[4] = {T[i].x, T[i].y, T[i].z, T[i].w};
#pragma unroll
    for (int k = 0; k < 4; ++k) {
      float x0 = x0s[k], x1 = x1s[k], x2 = x2s[k];
      int tv = tvs[k];
      float m  = fmaxf(x0, fmaxf(x1, x2));
      float e0 = __expf(x0 - m), e1 = __expf(x1 - m), e2 = __expf(x2 - m);
      float s  = e0 + e1 + e2;
      float ls = __logf(s);
      float xt = (tv == 0) ? x0 : ((tv == 1) ? x1 : x2);
      ce += (m + ls) - xt;  // -= logp[target]
      // trunc(softmax prob) == 1 iff e_i carries the whole f32 sum (prob
      // rounds to exactly 1.0). Needs logit gap > ~16.6; never for N(0,1).
      int t0 = (e0 >= s) ? 1 : 0;
      int t1 = (e1 >= s) ? 1 : 0;
      int t2 = (e2 >= s) ? 1 : 0;
      pkA += ((tv == 1) ? 1 : 0) + ((tv == 2) ? (1 << 16) : 0);
      pkB += t0 + (t1 << 16);
      pkC += t2 + (((tv == 0) ? t0 : 0) << 16);
      pkD += ((tv == 1) ? t1 : 0) + (((tv == 2) ? t2 : 0) << 16);
    }
  }

  // Block reduction of 5 channels: wave shuffle then cross-wave LDS.
  int pks[4] = {pkA, pkB, pkC, pkD};
#pragma unroll
  for (int off = 32; off > 0; off >>= 1) {
    ce += __shfl_down(ce, off, 64);
#pragma unroll
    for (int k = 0; k < 4; ++k) pks[k] += __shfl_down(pks[k], off, 64);
  }

  __shared__ float ceR[THREADS / 64];
  __shared__ int   pkR[THREADS / 64][4];
  const int wave = t >> 6, lane = t & 63;
  if (lane == 0) {
    ceR[wave] = ce;
#pragma unroll
    for (int k = 0; k < 4; ++k) pkR[wave][k] = pks[k];
  }
  __syncthreads();
  if (t == 0) {
#pragma unroll
    for (int w = 1; w < THREADS / 64; ++w) {
      ce += ceR[w];
#pragma unroll
      for (int k = 0; k < 4; ++k) pks[k] += pkR[w][k];
    }
    float4* rec = (float4*)(ws + (size_t)blockIdx.x * REC);
    rec[0] = make_float4(ce, __int_as_float(pks[0]), __int_as_float(pks[1]),
                         __int_as_float(pks[2]));
    rec[1] = make_float4(__int_as_float(pks[3]), 0.f, 0.f, 0.f);
  }
}

// One wave per image reduces its 128 block records (2 per lane).
__global__ __launch_bounds__(1024) void dice_ce_final(
    const float* __restrict__ ws, float* __restrict__ out) {
  const int t = threadIdx.x;        // 0..1023
  const int img = t >> 6;           // one wave per image
  const int lane = t & 63;

  float ce = 0.f;
  float cnt1 = 0.f, cnt2 = 0.f;
  float tps0 = 0.f, tps1 = 0.f, tps2 = 0.f;
  float itr0 = 0.f, itr1 = 0.f, itr2 = 0.f;
#pragma unroll
  for (int r = 0; r < 2; ++r) {
    const int idx = img * BLOCKS_PER_IMG + r * 64 + lane;
    const float4* rec = (const float4*)(ws + (size_t)idx * REC);
    float4 r0 = rec[0], r1 = rec[1];
    ce += r0.x;
    int pA = __float_as_int(r0.y), pB = __float_as_int(r0.z);
    int pC = __float_as_int(r0.w), pD = __float_as_int(r1.x);
    cnt1 += (float)(pA & 0xffff); cnt2 += (float)(pA >> 16);
    tps0 += (float)(pB & 0xffff); tps1 += (float)(pB >> 16);
    tps2 += (float)(pC & 0xffff); itr0 += (float)(pC >> 16);
    itr1 += (float)(pD & 0xffff); itr2 += (float)(pD >> 16);
  }
  float v[9] = {ce, cnt1, cnt2, tps0, tps1, tps2, itr0, itr1, itr2};
#pragma unroll
  for (int k = 0; k < 9; ++k) {
#pragma unroll
    for (int off = 32; off > 0; off >>= 1) v[k] += __shfl_down(v[k], off, 64);
  }

  __shared__ float ceS[16];
  __shared__ float coefS[16];
  if (lane == 0) {
    float c1 = v[1], c2 = v[2];
    float c0 = (float)HW_ - c1 - c2;
    float coef = (2.f * v[6] + 1.f) / (v[3] + c0 + 1.f)
               + (2.f * v[7] + 1.f) / (v[4] + c1 + 1.f)
               + (2.f * v[8] + 1.f) / (v[5] + c2 + 1.f);
    ceS[img] = v[0];
    coefS[img] = coef;
  }
  __syncthreads();
  if (t == 0) {
    float cesum = 0.f, cf = 0.f;
#pragma unroll
    for (int i = 0; i < 16; ++i) { cesum += ceS[i]; cf += coefS[i]; }
    out[0] = cesum / ((float)B_ * (float)HW_) + 1.f - cf / (float)(B_ * C_);
  }
}

extern "C" void kernel_launch(void* const* d_in, const int* in_sizes, int n_in,
                              void* d_out, int out_size, void* d_ws, size_t ws_size,
                              hipStream_t stream) {
  const float* pred = (const float*)d_in[0];
  const int*   tgt  = (const int*)d_in[1];
  float*       out  = (float*)d_out;
  float*       ws   = (float*)d_ws;

  dice_ce_partial<<<NBLOCKS, THREADS, 0, stream>>>(pred, tgt, ws);
  dice_ce_final<<<1, 1024, 0, stream>>>(ws, out);
}